// Round 2
// baseline (570.126 us; speedup 1.0000x reference)
//
#include <hip/hip_runtime.h>
#include <stdint.h>

// Problem constants
#define B_  16
#define N_  1024
#define C_  1024
#define H_  16
#define D_  64
#define P_  16
#define M_  1040           // P + N
#define MP_ 1088           // M padded to 17*64

typedef __attribute__((ext_vector_type(8))) short short8;   // 8 bf16 = 4 VGPRs
typedef __attribute__((ext_vector_type(4))) float f32x4;    // MFMA C/D frag

__device__ __forceinline__ unsigned short f2bf(float f) {
  unsigned int u = __float_as_uint(f);
  u += 0x7fffu + ((u >> 16) & 1u);          // RNE
  return (unsigned short)(u >> 16);
}
__device__ __forceinline__ float bf2f(unsigned short b) {
  return __uint_as_float(((unsigned int)b) << 16);
}

// async global->LDS, 16B per lane. LDS dest must be wave-uniform base (+lane*16 implicit).
__device__ __forceinline__ void async_cp16(void* lds, const void* g) {
  __builtin_amdgcn_global_load_lds(
      (__attribute__((address_space(1))) void*)(void*)g,
      (__attribute__((address_space(3))) void*)lds,
      16, 0, 0);
}

// ---------------- prep kernels ----------------

__global__ void cast_x_kernel(const float* __restrict__ x, unsigned short* __restrict__ xb) {
  int i = (blockIdx.x * 256 + threadIdx.x) * 4;
  float4 v = *(const float4*)(x + i);
  ushort4 o;
  o.x = f2bf(v.x); o.y = f2bf(v.y); o.z = f2bf(v.z); o.w = f2bf(v.w);
  *(ushort4*)(xb + i) = o;
}

// in [1024][cols] fp32 -> out [cols][1024] bf16  (read strided, write coalesced; L2/L3 absorb)
__global__ void transpose_cast_kernel(const float* __restrict__ in,
                                      unsigned short* __restrict__ out, int cols) {
  int o = blockIdx.x * 256 + threadIdx.x;
  int n = o >> 10, k = o & 1023;
  out[o] = f2bf(in[(size_t)k * cols + n]);
}

// prefix rows 0..15 from pk/pv, zero pad rows 1040..1087
__global__ void prefix_pad_kernel(const float* __restrict__ pk, const float* __restrict__ pv,
                                  unsigned short* __restrict__ Kw, unsigned short* __restrict__ Vw) {
  int idx = blockIdx.x * 256 + threadIdx.x;   // 256 bh * 64 rr * 64 d = 1,048,576
  int d  = idx & 63;
  int rr = (idx >> 6) & 63;
  int bh = idx >> 12;
  int row = (rr < P_) ? rr : (1024 + rr);     // 16..63 -> 1040..1087
  float kv = 0.f, vv = 0.f;
  if (rr < P_) {
    int b = bh >> 4, h = bh & 15;
    int src = (b * P_ + rr) * C_ + h * D_ + d;
    kv = pk[src]; vv = pv[src];
  }
  size_t dst = ((size_t)bh * MP_ + row) * D_ + d;
  Kw[dst] = f2bf(kv);
  Vw[dst] = f2bf(vv);
}

// Vw [bh][MP][64] -> Vt [bh][64][MP]
__global__ void vt_kernel(const unsigned short* __restrict__ Vw, unsigned short* __restrict__ Vt) {
  __shared__ unsigned short t[64][65];
  int mt = blockIdx.x;           // 17
  int bh = blockIdx.y;           // 256
  int tid = threadIdx.x;
  const unsigned short* src = Vw + ((size_t)bh * MP_ + mt * 64) * 64;
#pragma unroll
  for (int i = 0; i < 16; ++i) {
    int e = i * 256 + tid;
    t[e >> 6][e & 63] = src[e];
  }
  __syncthreads();
  unsigned short* dst = Vt + (size_t)bh * 64 * MP_ + mt * 64;
#pragma unroll
  for (int i = 0; i < 16; ++i) {
    int e = i * 256 + tid;
    int d = e >> 6, m = e & 63;
    dst[(size_t)d * MP_ + m] = t[m][d];
  }
}

// ---------------- GEMM: C[M,Ncols] = A[M,1024] * Bt[Ncols,1024]^T ----------------
// 128x128 tile, BK=32, 16x16x32 bf16 MFMA, global_load_lds staging (m97 structure).
// MODE 0: qkv epilogue (scatter to Qw (pre-scaled), Kw, Vw).  MODE 1: proj epilogue (+bias, FP32 out).
template <int MODE>
__global__ __launch_bounds__(256) void gemm128(const unsigned short* __restrict__ A,
                                               const unsigned short* __restrict__ Bt,
                                               unsigned short* __restrict__ Qw,
                                               unsigned short* __restrict__ Kw,
                                               unsigned short* __restrict__ Vw,
                                               const float* __restrict__ bias,
                                               float* __restrict__ Out) {
  __shared__ unsigned short As[128 * 32];
  __shared__ unsigned short Bs[128 * 32];
  const int tid = threadIdx.x;
  const int w = tid >> 6, lane = tid & 63;
  const int l15 = lane & 15, quad = lane >> 4, q8 = quad * 8;
  const int wm = w & 1, wn = w >> 1;
  const int rt = blockIdx.x, ct = blockIdx.y;

  f32x4 acc[4][4] = {};
  const unsigned short* Abase = A + (size_t)rt * 128 * 1024;
  const unsigned short* Bbase = Bt + (size_t)ct * 128 * 1024;

  for (int k0 = 0; k0 < 1024; k0 += 32) {
    __syncthreads();            // protect LDS from prior-iteration readers
#pragma unroll
    for (int r = 0; r < 2; ++r) {
      int c = r * 256 + tid;                 // 512 chunks of 16B per 8KB tile
      int m = c >> 2, kq = (c & 3) * 8;
      async_cp16(&As[(r * 256 + (w << 6)) * 8], Abase + m * 1024 + k0 + kq);
      async_cp16(&Bs[(r * 256 + (w << 6)) * 8], Bbase + m * 1024 + k0 + kq);
    }
    __syncthreads();            // drains vmcnt (global_load_lds) before reads

    short8 av[4], bv[4];
#pragma unroll
    for (int mt = 0; mt < 4; ++mt)
      av[mt] = *(const short8*)&As[(wm * 64 + mt * 16 + l15) * 32 + q8];
#pragma unroll
    for (int nt = 0; nt < 4; ++nt)
      bv[nt] = *(const short8*)&Bs[(wn * 64 + nt * 16 + l15) * 32 + q8];
#pragma unroll
    for (int mt = 0; mt < 4; ++mt)
#pragma unroll
      for (int nt = 0; nt < 4; ++nt)
        acc[mt][nt] = __builtin_amdgcn_mfma_f32_16x16x32_bf16(av[mt], bv[nt], acc[mt][nt], 0, 0, 0);
  }

  // epilogue: C/D layout col = l15, row = quad*4 + r
  if (MODE == 0) {
    int b = rt >> 3;   // 128-row tiles align with batch boundaries
#pragma unroll
    for (int nt = 0; nt < 4; ++nt) {
      int col = ct * 128 + wn * 64 + nt * 16 + l15;
      int sel = col >> 10;
      int h = (col >> 6) & 15;
      int d = col & 63;
      int bh = b * 16 + h;
#pragma unroll
      for (int mt = 0; mt < 4; ++mt) {
#pragma unroll
        for (int r = 0; r < 4; ++r) {
          int row = rt * 128 + wm * 64 + mt * 16 + quad * 4 + r;
          int n = row & 1023;
          float v = acc[mt][nt][r];
          if (sel == 0) {
            Qw[((size_t)bh * N_ + n) * D_ + d] = f2bf(v * 0.125f);  // fold softmax scale into q
          } else if (sel == 1) {
            Kw[((size_t)bh * MP_ + P_ + n) * D_ + d] = f2bf(v);
          } else {
            Vw[((size_t)bh * MP_ + P_ + n) * D_ + d] = f2bf(v);
          }
        }
      }
    }
  } else {
#pragma unroll
    for (int nt = 0; nt < 4; ++nt) {
      int col = ct * 128 + wn * 64 + nt * 16 + l15;
      float bs = bias[col];
#pragma unroll
      for (int mt = 0; mt < 4; ++mt) {
#pragma unroll
        for (int r = 0; r < 4; ++r) {
          int row = rt * 128 + wm * 64 + mt * 16 + quad * 4 + r;
          Out[(size_t)row * C_ + col] = acc[mt][nt][r] + bs;   // d_out is FP32 (reference dtype)
        }
      }
    }
  }
}

// ---------------- attention ----------------
// grid (16 q-tiles, 256 bh), block 256 (4 waves, 16 q-rows each).
// Scores are bounded (|s| < ~4) -> exp without max subtraction; no online rescale needed.
__global__ __launch_bounds__(256) void attn_kernel(const unsigned short* __restrict__ Qw,
                                                   const unsigned short* __restrict__ Kw,
                                                   const unsigned short* __restrict__ Vt,
                                                   unsigned short* __restrict__ Ao) {
  __shared__ unsigned short Ks[64 * 64];
  __shared__ unsigned short Vs[64 * 64];
  __shared__ unsigned short Ps[4][16 * 64];   // per-wave P round-trip buffer
  const int tid = threadIdx.x;
  const int w = tid >> 6, lane = tid & 63;
  const int l15 = lane & 15, quad = lane >> 4, q8 = quad * 8;
  const int qt = blockIdx.x, bh = blockIdx.y;

  // Q A-frags: rows qt*64 + w*16 + l15, q pre-scaled by 1/8
  const unsigned short* Qbase = Qw + ((size_t)bh * N_ + qt * 64 + w * 16 + l15) * 64;
  short8 aq0 = *(const short8*)&Qbase[q8];
  short8 aq1 = *(const short8*)&Qbase[32 + q8];

  f32x4 oacc[4] = {};
  float den[4] = {0.f, 0.f, 0.f, 0.f};

  const unsigned short* Kbh = Kw + (size_t)bh * MP_ * 64;
  const unsigned short* Vbh = Vt + (size_t)bh * 64 * MP_;

  for (int ch = 0; ch < 17; ++ch) {
    __syncthreads();
    const unsigned short* Ksrc = Kbh + ch * 64 * 64;  // contiguous 8KB chunk
#pragma unroll
    for (int r = 0; r < 2; ++r) {
      int c = r * 256 + tid;
      async_cp16(&Ks[(r * 256 + (w << 6)) * 8], Ksrc + c * 8);
      int drow = c >> 3, seg = (c & 7) * 8;
      async_cp16(&Vs[(r * 256 + (w << 6)) * 8], Vbh + (size_t)drow * MP_ + ch * 64 + seg);
    }
    __syncthreads();

    // S = Q K^T  (n = key col, k = d)
    f32x4 s[4] = {};
#pragma unroll
    for (int ct2 = 0; ct2 < 4; ++ct2) {
      short8 b0 = *(const short8*)&Ks[(ct2 * 16 + l15) * 64 + q8];
      short8 b1 = *(const short8*)&Ks[(ct2 * 16 + l15) * 64 + 32 + q8];
      s[ct2] = __builtin_amdgcn_mfma_f32_16x16x32_bf16(aq0, b0, s[ct2], 0, 0, 0);
      s[ct2] = __builtin_amdgcn_mfma_f32_16x16x32_bf16(aq1, b1, s[ct2], 0, 0, 0);
    }

    // exp + pad mask; write P (C/D layout -> [q][m] row-major in per-wave LDS)
    unsigned short* Pw = &Ps[w][0];
    int mbase = ch * 64;
#pragma unroll
    for (int ct2 = 0; ct2 < 4; ++ct2) {
      int mg = mbase + ct2 * 16 + l15;
      bool valid = (mg < M_);
#pragma unroll
      for (int r = 0; r < 4; ++r) {
        float p = valid ? __expf(s[ct2][r]) : 0.f;
        unsigned short pu = f2bf(p);
        den[r] += bf2f(pu);                 // denominator matches the quantized numerator
        Pw[(quad * 4 + r) * 64 + ct2 * 16 + l15] = pu;
      }
    }

    // P A-frags (m = l15, k = m-col)
    short8 ap0 = *(const short8*)&Pw[l15 * 64 + q8];
    short8 ap1 = *(const short8*)&Pw[l15 * 64 + 32 + q8];

    // O += P * V   (B-frag from transposed V: n = d, k = m)
#pragma unroll
    for (int dt = 0; dt < 4; ++dt) {
      short8 b0 = *(const short8*)&Vs[(dt * 16 + l15) * 64 + q8];
      short8 b1 = *(const short8*)&Vs[(dt * 16 + l15) * 64 + 32 + q8];
      oacc[dt] = __builtin_amdgcn_mfma_f32_16x16x32_bf16(ap0, b0, oacc[dt], 0, 0, 0);
      oacc[dt] = __builtin_amdgcn_mfma_f32_16x16x32_bf16(ap1, b1, oacc[dt], 0, 0, 0);
    }
  }

  // reduce denominator across the 16 lanes sharing each q-row
#pragma unroll
  for (int r = 0; r < 4; ++r) {
    float d2 = den[r];
    d2 += __shfl_xor(d2, 1);
    d2 += __shfl_xor(d2, 2);
    d2 += __shfl_xor(d2, 4);
    d2 += __shfl_xor(d2, 8);
    den[r] = 1.f / d2;
  }

  int b = bh >> 4, h = bh & 15;
#pragma unroll
  for (int dt = 0; dt < 4; ++dt) {
#pragma unroll
    for (int r = 0; r < 4; ++r) {
      int qrow = qt * 64 + w * 16 + quad * 4 + r;
      size_t dst = ((size_t)(b * N_ + qrow)) * C_ + h * 64 + dt * 16 + l15;
      Ao[dst] = f2bf(oacc[dt][r] * den[r]);
    }
  }
}

// ---------------- launch ----------------

extern "C" void kernel_launch(void* const* d_in, const int* in_sizes, int n_in,
                              void* d_out, int out_size, void* d_ws, size_t ws_size,
                              hipStream_t stream) {
  const float* x      = (const float*)d_in[0];
  const float* pk     = (const float*)d_in[1];
  const float* pv     = (const float*)d_in[2];
  const float* w_qkv  = (const float*)d_in[3];
  const float* w_proj = (const float*)d_in[4];
  const float* b_proj = (const float*)d_in[5];

  char* ws = (char*)d_ws;
  unsigned short* xb     = (unsigned short*)(ws);                 // 33,554,432 B
  unsigned short* wqkvT  = (unsigned short*)(ws + 33554432);      //  6,291,456 B
  unsigned short* wprojT = (unsigned short*)(ws + 39845888);      //  2,097,152 B
  unsigned short* Qw     = (unsigned short*)(ws + 41943040);      // 33,554,432 B
  unsigned short* Kw     = (unsigned short*)(ws + 75497472);      // 35,651,584 B
  unsigned short* Vw     = (unsigned short*)(ws + 111149056);     // 35,651,584 B
  unsigned short* Vt     = (unsigned short*)(ws + 146800640);     // 35,651,584 B
  unsigned short* attn   = xb;  // alias: xb is dead after the QKV GEMM

  cast_x_kernel<<<16384, 256, 0, stream>>>(x, xb);
  transpose_cast_kernel<<<(3072 * 1024) / 256, 256, 0, stream>>>(w_qkv, wqkvT, 3072);
  transpose_cast_kernel<<<(1024 * 1024) / 256, 256, 0, stream>>>(w_proj, wprojT, 1024);
  prefix_pad_kernel<<<4096, 256, 0, stream>>>(pk, pv, Kw, Vw);

  gemm128<0><<<dim3(128, 24), 256, 0, stream>>>(xb, wqkvT, Qw, Kw, Vw, nullptr, nullptr);
  vt_kernel<<<dim3(17, 256), 256, 0, stream>>>(Vw, Vt);
  attn_kernel<<<dim3(16, 256), 256, 0, stream>>>(Qw, Kw, Vt, attn);
  gemm128<1><<<dim3(128, 8), 256, 0, stream>>>(attn, wprojT, nullptr, nullptr, nullptr,
                                               b_proj, (float*)d_out);
}

// Round 3
// 462.225 us; speedup vs baseline: 1.2334x; 1.2334x over previous
//
#include <hip/hip_runtime.h>
#include <stdint.h>

// Problem constants
#define B_  16
#define N_  1024
#define C_  1024
#define H_  16
#define D_  64
#define P_  16
#define M_  1040           // P + N
#define MP_ 1088           // M padded to 17*64

typedef __attribute__((ext_vector_type(8))) short short8;   // 8 bf16 = 4 VGPRs
typedef __attribute__((ext_vector_type(4))) float f32x4;    // MFMA C/D frag

__device__ __forceinline__ unsigned short f2bf(float f) {
  unsigned int u = __float_as_uint(f);
  u += 0x7fffu + ((u >> 16) & 1u);          // RNE
  return (unsigned short)(u >> 16);
}

// async global->LDS, 16B per lane. LDS dest must be wave-uniform base (+lane*16 implicit).
__device__ __forceinline__ void async_cp16(void* lds, const void* g) {
  __builtin_amdgcn_global_load_lds(
      (__attribute__((address_space(1))) void*)(void*)g,
      (__attribute__((address_space(3))) void*)lds,
      16, 0, 0);
}

// ---------------- prep kernels ----------------

__global__ void cast_x_kernel(const float* __restrict__ x, unsigned short* __restrict__ xb) {
  int i = (blockIdx.x * 256 + threadIdx.x) * 4;
  float4 v = *(const float4*)(x + i);
  ushort4 o;
  o.x = f2bf(v.x); o.y = f2bf(v.y); o.z = f2bf(v.z); o.w = f2bf(v.w);
  *(ushort4*)(xb + i) = o;
}

// in [1024 k][cols n] fp32 -> out [cols n][1024 k] bf16, 64x64 LDS tiles (both sides coalesced)
__global__ void transpose_cast_kernel(const float* __restrict__ in,
                                      unsigned short* __restrict__ out, int cols) {
  __shared__ unsigned short t[64][68];   // pad 68: breaks bank aliasing on strided read
  int n0 = blockIdx.x * 64, k0 = blockIdx.y * 64;
  int tid = threadIdx.x;
#pragma unroll
  for (int i = 0; i < 16; ++i) {
    int e = i * 256 + tid;
    int kk = e >> 6, nn = e & 63;
    t[kk][nn] = f2bf(in[(size_t)(k0 + kk) * cols + n0 + nn]);
  }
  __syncthreads();
#pragma unroll
  for (int i = 0; i < 16; ++i) {
    int e = i * 256 + tid;
    int nn = e >> 6, kk = e & 63;
    out[(size_t)(n0 + nn) * 1024 + k0 + kk] = t[kk][nn];
  }
}

// prefix rows 0..15 from pk/pv, zero pad rows 1040..1087.
// K in [bh][MP][64]; V in transposed [bh][64][MP] layout.
__global__ void prefix_pad_kernel(const float* __restrict__ pk, const float* __restrict__ pv,
                                  unsigned short* __restrict__ Kw, unsigned short* __restrict__ Vt) {
  int idx = blockIdx.x * 256 + threadIdx.x;   // 1,048,576
  {  // K: d fastest (coalesced dst + src)
    int d = idx & 63, rr = (idx >> 6) & 63, bh = idx >> 12;
    int row = (rr < P_) ? rr : (1024 + rr);
    float kv = 0.f;
    if (rr < P_) { int b = bh >> 4, h = bh & 15; kv = pk[(b * P_ + rr) * C_ + h * D_ + d]; }
    Kw[((size_t)bh * MP_ + row) * D_ + d] = f2bf(kv);
  }
  {  // V^T: row-slot fastest (coalesced dst; tiny strided src absorbed by L2)
    int mm = idx & 63, d = (idx >> 6) & 63, bh = idx >> 12;
    int row = (mm < P_) ? mm : (1024 + mm);
    float vv = 0.f;
    if (mm < P_) { int b = bh >> 4, h = bh & 15; vv = pv[(b * P_ + mm) * C_ + h * D_ + d]; }
    Vt[((size_t)bh * D_ + d) * MP_ + row] = f2bf(vv);
  }
}

// ---------------- GEMM: C[M,Ncols] = A[M,1024] * Bt[Ncols,1024]^T ----------------
// 128x128 tile, BK=32, 16x16x32 bf16 MFMA, global_load_lds staging (m97 structure).
// MODE 0: qkv epilogue (Qw pre-scaled, Kw, V^T direct). MODE 1: proj epilogue (+bias, FP32 out).
template <int MODE>
__global__ __launch_bounds__(256) void gemm128(const unsigned short* __restrict__ A,
                                               const unsigned short* __restrict__ Bt,
                                               unsigned short* __restrict__ Qw,
                                               unsigned short* __restrict__ Kw,
                                               unsigned short* __restrict__ Vt,
                                               const float* __restrict__ bias,
                                               float* __restrict__ Out) {
  __shared__ unsigned short As[128 * 32];
  __shared__ unsigned short Bs[128 * 32];
  const int tid = threadIdx.x;
  const int w = tid >> 6, lane = tid & 63;
  const int l15 = lane & 15, quad = lane >> 4, q8 = quad * 8;
  const int wm = w & 1, wn = w >> 1;
  const int rt = blockIdx.x, ct = blockIdx.y;

  f32x4 acc[4][4] = {};
  const unsigned short* Abase = A + (size_t)rt * 128 * 1024;
  const unsigned short* Bbase = Bt + (size_t)ct * 128 * 1024;

  for (int k0 = 0; k0 < 1024; k0 += 32) {
    __syncthreads();
#pragma unroll
    for (int r = 0; r < 2; ++r) {
      int c = r * 256 + tid;                 // 512 chunks of 16B per 8KB tile
      int m = c >> 2, kq = (c & 3) * 8;
      async_cp16(&As[(r * 256 + (w << 6)) * 8], Abase + m * 1024 + k0 + kq);
      async_cp16(&Bs[(r * 256 + (w << 6)) * 8], Bbase + m * 1024 + k0 + kq);
    }
    __syncthreads();

    short8 av[4], bv[4];
#pragma unroll
    for (int mt = 0; mt < 4; ++mt)
      av[mt] = *(const short8*)&As[(wm * 64 + mt * 16 + l15) * 32 + q8];
#pragma unroll
    for (int nt = 0; nt < 4; ++nt)
      bv[nt] = *(const short8*)&Bs[(wn * 64 + nt * 16 + l15) * 32 + q8];
#pragma unroll
    for (int mt = 0; mt < 4; ++mt)
#pragma unroll
      for (int nt = 0; nt < 4; ++nt)
        acc[mt][nt] = __builtin_amdgcn_mfma_f32_16x16x32_bf16(av[mt], bv[nt], acc[mt][nt], 0, 0, 0);
  }

  // epilogue: C/D layout col = l15, row = quad*4 + r
  if (MODE == 0) {
    int b = rt >> 3;   // 128-row tiles align with batch boundaries
#pragma unroll
    for (int nt = 0; nt < 4; ++nt) {
      int col = ct * 128 + wn * 64 + nt * 16 + l15;
      int sel = col >> 10;
      int h = (col >> 6) & 15;
      int d = col & 63;
      int bh = b * 16 + h;
#pragma unroll
      for (int mt = 0; mt < 4; ++mt) {
        int row0 = rt * 128 + wm * 64 + mt * 16 + quad * 4;
        int n0 = row0 & 1023;
        if (sel == 2) {
          // V^T: lane holds 4 consecutive n for fixed d -> one packed 8B store
          ushort4 p4;
          p4.x = f2bf(acc[mt][nt][0]); p4.y = f2bf(acc[mt][nt][1]);
          p4.z = f2bf(acc[mt][nt][2]); p4.w = f2bf(acc[mt][nt][3]);
          *(ushort4*)&Vt[((size_t)bh * D_ + d) * MP_ + P_ + n0] = p4;
        } else {
#pragma unroll
          for (int r = 0; r < 4; ++r) {
            float v = acc[mt][nt][r];
            int n = n0 + r;
            if (sel == 0)
              Qw[((size_t)bh * N_ + n) * D_ + d] = f2bf(v * 0.125f);  // fold softmax scale
            else
              Kw[((size_t)bh * MP_ + P_ + n) * D_ + d] = f2bf(v);
          }
        }
      }
    }
  } else {
#pragma unroll
    for (int nt = 0; nt < 4; ++nt) {
      int col = ct * 128 + wn * 64 + nt * 16 + l15;
      float bs = bias[col];
#pragma unroll
      for (int mt = 0; mt < 4; ++mt) {
#pragma unroll
        for (int r = 0; r < 4; ++r) {
          int row = rt * 128 + wm * 64 + mt * 16 + quad * 4 + r;
          Out[(size_t)row * C_ + col] = acc[mt][nt][r] + bs;   // d_out is FP32
        }
      }
    }
  }
}

// ---------------- attention ----------------
// grid (8 q-tiles, 256 bh), block 256 = 4 waves x 32 q-rows (128 q-rows/block).
// K/V chunks in split-panel LDS layout (64B rows -> conflict-free b128 reads, same
// pattern as the GEMM's BK=32 tiles). Ps stride 80 (160B, 16B-aligned, bank-spread).
__global__ __launch_bounds__(256) void attn_kernel(const unsigned short* __restrict__ Qw,
                                                   const unsigned short* __restrict__ Kw,
                                                   const unsigned short* __restrict__ Vt,
                                                   unsigned short* __restrict__ Ao) {
  __shared__ unsigned short Ks[4096];      // 2 panels [64 m][32 d]
  __shared__ unsigned short Vs[4096];      // 2 panels [64 d][32 m]
  __shared__ unsigned short Ps[4][32 * 80];
  const int tid = threadIdx.x;
  const int w = tid >> 6, lane = tid & 63;
  const int l15 = lane & 15, quad = lane >> 4, q8 = quad * 8;
  const int qt = blockIdx.x, bh = blockIdx.y;

  short8 aq[2][2];
#pragma unroll
  for (int mq = 0; mq < 2; ++mq) {
    const unsigned short* Qbase =
        Qw + ((size_t)bh * N_ + qt * 128 + w * 32 + mq * 16 + l15) * 64;
    aq[mq][0] = *(const short8*)&Qbase[q8];
    aq[mq][1] = *(const short8*)&Qbase[32 + q8];
  }

  f32x4 oacc[2][4] = {};
  float den[2][4] = {};

  const unsigned short* Kbh = Kw + (size_t)bh * MP_ * 64;
  const unsigned short* Vbh = Vt + (size_t)bh * 64 * MP_;

  for (int ch = 0; ch < 17; ++ch) {
    __syncthreads();
#pragma unroll
    for (int r = 0; r < 2; ++r) {
      int c = r * 256 + tid;
      int p = c >> 8, mrow = (c >> 2) & 63, s = c & 3;   // chunk -> (panel, row, 16B seg)
      async_cp16(&Ks[(r * 256 + (w << 6)) * 8], Kbh + (size_t)(ch * 64 + mrow) * 64 + p * 32 + s * 8);
      async_cp16(&Vs[(r * 256 + (w << 6)) * 8], Vbh + (size_t)mrow * MP_ + ch * 64 + p * 32 + s * 8);
    }
    __syncthreads();

    unsigned short* Pw = &Ps[w][0];
#pragma unroll
    for (int ct2 = 0; ct2 < 4; ++ct2) {
      short8 b0 = *(const short8*)&Ks[(ct2 * 16 + l15) * 32 + q8];         // d 0..31
      short8 b1 = *(const short8*)&Ks[2048 + (ct2 * 16 + l15) * 32 + q8];  // d 32..63
      int mg = ch * 64 + ct2 * 16 + l15;
      bool valid = (mg < M_);
#pragma unroll
      for (int mq = 0; mq < 2; ++mq) {
        f32x4 s = {};
        s = __builtin_amdgcn_mfma_f32_16x16x32_bf16(aq[mq][0], b0, s, 0, 0, 0);
        s = __builtin_amdgcn_mfma_f32_16x16x32_bf16(aq[mq][1], b1, s, 0, 0, 0);
#pragma unroll
        for (int r = 0; r < 4; ++r) {
          float p = valid ? __expf(s[r]) : 0.f;
          den[mq][r] += p;
          Pw[(mq * 16 + quad * 4 + r) * 80 + ct2 * 16 + l15] = f2bf(p);
        }
      }
    }

    short8 ap[2][2];
#pragma unroll
    for (int mq = 0; mq < 2; ++mq) {
      ap[mq][0] = *(const short8*)&Pw[(mq * 16 + l15) * 80 + q8];
      ap[mq][1] = *(const short8*)&Pw[(mq * 16 + l15) * 80 + 32 + q8];
    }
#pragma unroll
    for (int dt = 0; dt < 4; ++dt) {
      short8 b0 = *(const short8*)&Vs[(dt * 16 + l15) * 32 + q8];          // m 0..31
      short8 b1 = *(const short8*)&Vs[2048 + (dt * 16 + l15) * 32 + q8];   // m 32..63
#pragma unroll
      for (int mq = 0; mq < 2; ++mq) {
        oacc[mq][dt] = __builtin_amdgcn_mfma_f32_16x16x32_bf16(ap[mq][0], b0, oacc[mq][dt], 0, 0, 0);
        oacc[mq][dt] = __builtin_amdgcn_mfma_f32_16x16x32_bf16(ap[mq][1], b1, oacc[mq][dt], 0, 0, 0);
      }
    }
  }

  // reduce denominator across the 16 lanes sharing each q-row
#pragma unroll
  for (int mq = 0; mq < 2; ++mq)
#pragma unroll
    for (int r = 0; r < 4; ++r) {
      float d2 = den[mq][r];
      d2 += __shfl_xor(d2, 1);
      d2 += __shfl_xor(d2, 2);
      d2 += __shfl_xor(d2, 4);
      d2 += __shfl_xor(d2, 8);
      den[mq][r] = 1.f / d2;
    }

  int b = bh >> 4, h = bh & 15;
#pragma unroll
  for (int mq = 0; mq < 2; ++mq)
#pragma unroll
    for (int dt = 0; dt < 4; ++dt)
#pragma unroll
      for (int r = 0; r < 4; ++r) {
        int qrow = qt * 128 + w * 32 + mq * 16 + quad * 4 + r;
        size_t dst = ((size_t)(b * N_ + qrow)) * C_ + h * 64 + dt * 16 + l15;
        Ao[dst] = f2bf(oacc[mq][dt][r] * den[mq][r]);
      }
}

// ---------------- launch ----------------

extern "C" void kernel_launch(void* const* d_in, const int* in_sizes, int n_in,
                              void* d_out, int out_size, void* d_ws, size_t ws_size,
                              hipStream_t stream) {
  const float* x      = (const float*)d_in[0];
  const float* pk     = (const float*)d_in[1];
  const float* pv     = (const float*)d_in[2];
  const float* w_qkv  = (const float*)d_in[3];
  const float* w_proj = (const float*)d_in[4];
  const float* b_proj = (const float*)d_in[5];

  char* ws = (char*)d_ws;
  unsigned short* xb     = (unsigned short*)(ws);                 // 33,554,432 B
  unsigned short* wqkvT  = (unsigned short*)(ws + 33554432);      //  6,291,456 B
  unsigned short* wprojT = (unsigned short*)(ws + 39845888);      //  2,097,152 B
  unsigned short* Qw     = (unsigned short*)(ws + 41943040);      // 33,554,432 B
  unsigned short* Kw     = (unsigned short*)(ws + 75497472);      // 35,651,584 B
  unsigned short* Vt     = (unsigned short*)(ws + 111149056);     // 35,651,584 B
  unsigned short* attn   = xb;  // alias: xb is dead after the QKV GEMM

  cast_x_kernel<<<16384, 256, 0, stream>>>(x, xb);
  transpose_cast_kernel<<<dim3(48, 16), 256, 0, stream>>>(w_qkv, wqkvT, 3072);
  transpose_cast_kernel<<<dim3(16, 16), 256, 0, stream>>>(w_proj, wprojT, 1024);
  prefix_pad_kernel<<<4096, 256, 0, stream>>>(pk, pv, Kw, Vt);

  gemm128<0><<<dim3(128, 24), 256, 0, stream>>>(xb, wqkvT, Qw, Kw, Vt, nullptr, nullptr);
  attn_kernel<<<dim3(8, 256), 256, 0, stream>>>(Qw, Kw, Vt, attn);
  gemm128<1><<<dim3(128, 8), 256, 0, stream>>>(attn, wprojT, nullptr, nullptr, nullptr,
                                               b_proj, (float*)d_out);
}

// Round 4
// 451.299 us; speedup vs baseline: 1.2633x; 1.0242x over previous
//
#include <hip/hip_runtime.h>
#include <stdint.h>

// Problem constants
#define B_  16
#define N_  1024
#define C_  1024
#define H_  16
#define D_  64
#define P_  16
#define M_  1040           // P + N
#define MP_ 1088           // M padded to 17*64

typedef __attribute__((ext_vector_type(8))) short short8;   // 8 bf16 = 4 VGPRs
typedef __attribute__((ext_vector_type(4))) float f32x4;    // MFMA C/D frag

__device__ __forceinline__ unsigned short f2bf(float f) {
  unsigned int u = __float_as_uint(f);
  u += 0x7fffu + ((u >> 16) & 1u);          // RNE
  return (unsigned short)(u >> 16);
}

// async global->LDS, 16B per lane. LDS dest must be wave-uniform base (+lane*16 implicit).
__device__ __forceinline__ void async_cp16(void* lds, const void* g) {
  __builtin_amdgcn_global_load_lds(
      (__attribute__((address_space(1))) void*)(void*)g,
      (__attribute__((address_space(3))) void*)lds,
      16, 0, 0);
}

// ---------------- prep kernels ----------------

__global__ void cast_x_kernel(const float* __restrict__ x, unsigned short* __restrict__ xb) {
  int i = (blockIdx.x * 256 + threadIdx.x) * 4;
  float4 v = *(const float4*)(x + i);
  ushort4 o;
  o.x = f2bf(v.x); o.y = f2bf(v.y); o.z = f2bf(v.z); o.w = f2bf(v.w);
  *(ushort4*)(xb + i) = o;
}

// in [1024 k][cols n] fp32 -> out [cols n][1024 k] bf16, 64x64 LDS tiles (both sides coalesced)
__global__ void transpose_cast_kernel(const float* __restrict__ in,
                                      unsigned short* __restrict__ out, int cols) {
  __shared__ unsigned short t[64][68];   // pad 68: breaks bank aliasing on strided read
  int n0 = blockIdx.x * 64, k0 = blockIdx.y * 64;
  int tid = threadIdx.x;
#pragma unroll
  for (int i = 0; i < 16; ++i) {
    int e = i * 256 + tid;
    int kk = e >> 6, nn = e & 63;
    t[kk][nn] = f2bf(in[(size_t)(k0 + kk) * cols + n0 + nn]);
  }
  __syncthreads();
#pragma unroll
  for (int i = 0; i < 16; ++i) {
    int e = i * 256 + tid;
    int nn = e >> 6, kk = e & 63;
    out[(size_t)(n0 + nn) * 1024 + k0 + kk] = t[kk][nn];
  }
}

// prefix rows 0..15 from pk/pv, zero pad rows 1040..1087.
// K in [bh][MP][64]; V in transposed [bh][64][MP] layout.
__global__ void prefix_pad_kernel(const float* __restrict__ pk, const float* __restrict__ pv,
                                  unsigned short* __restrict__ Kw, unsigned short* __restrict__ Vt) {
  int idx = blockIdx.x * 256 + threadIdx.x;   // 1,048,576
  {  // K: d fastest (coalesced dst + src)
    int d = idx & 63, rr = (idx >> 6) & 63, bh = idx >> 12;
    int row = (rr < P_) ? rr : (1024 + rr);
    float kv = 0.f;
    if (rr < P_) { int b = bh >> 4, h = bh & 15; kv = pk[(b * P_ + rr) * C_ + h * D_ + d]; }
    Kw[((size_t)bh * MP_ + row) * D_ + d] = f2bf(kv);
  }
  {  // V^T: row-slot fastest (coalesced dst; tiny strided src absorbed by L2)
    int mm = idx & 63, d = (idx >> 6) & 63, bh = idx >> 12;
    int row = (mm < P_) ? mm : (1024 + mm);
    float vv = 0.f;
    if (mm < P_) { int b = bh >> 4, h = bh & 15; vv = pv[(b * P_ + mm) * C_ + h * D_ + d]; }
    Vt[((size_t)bh * D_ + d) * MP_ + row] = f2bf(vv);
  }
}

// ---------------- GEMM: C[M,Ncols] = A[M,1024] * Bt[Ncols,1024]^T ----------------
// 128x128 tile, BK=32, 16x16x32 bf16 MFMA, global_load_lds staging (m97 structure).
// 1-D grid with 32rt x 8ct supertile swizzle: a 256-block window touches A 8MB + B 2MB,
// and per-XCD (id%8 round-robin) only 4 A-panels + 8 B-panels = 3MB < 4MB L2.
// MODE 0: qkv epilogue (Q^T pre-scaled, Kw, V^T). MODE 1: proj epilogue (+bias, FP32 out).
template <int MODE>
__global__ __launch_bounds__(256) void gemm128(const unsigned short* __restrict__ A,
                                               const unsigned short* __restrict__ Bt,
                                               unsigned short* __restrict__ Qt,
                                               unsigned short* __restrict__ Kw,
                                               unsigned short* __restrict__ Vt,
                                               const float* __restrict__ bias,
                                               float* __restrict__ Out) {
  __shared__ unsigned short As[128 * 32];
  __shared__ unsigned short Bs[128 * 32];
  const int tid = threadIdx.x;
  const int w = tid >> 6, lane = tid & 63;
  const int l15 = lane & 15, quad = lane >> 4, q8 = quad * 8;
  const int wm = w & 1, wn = w >> 1;

  // supertile swizzle (RT=128 rows of tiles in both modes)
  const int id = blockIdx.x;
  const int st = id >> 8, local = id & 255;
  const int rt = (st & 3) * 32 + (local & 31);
  const int ct = (st >> 2) * 8 + (local >> 5);

  f32x4 acc[4][4] = {};
  const unsigned short* Abase = A + (size_t)rt * 128 * 1024;
  const unsigned short* Bbase = Bt + (size_t)ct * 128 * 1024;

  for (int k0 = 0; k0 < 1024; k0 += 32) {
    __syncthreads();
#pragma unroll
    for (int r = 0; r < 2; ++r) {
      int c = r * 256 + tid;                 // 512 chunks of 16B per 8KB tile
      int m = c >> 2, kq = (c & 3) * 8;
      async_cp16(&As[(r * 256 + (w << 6)) * 8], Abase + m * 1024 + k0 + kq);
      async_cp16(&Bs[(r * 256 + (w << 6)) * 8], Bbase + m * 1024 + k0 + kq);
    }
    __syncthreads();

    short8 av[4], bv[4];
#pragma unroll
    for (int mt = 0; mt < 4; ++mt)
      av[mt] = *(const short8*)&As[(wm * 64 + mt * 16 + l15) * 32 + q8];
#pragma unroll
    for (int nt = 0; nt < 4; ++nt)
      bv[nt] = *(const short8*)&Bs[(wn * 64 + nt * 16 + l15) * 32 + q8];
#pragma unroll
    for (int mt = 0; mt < 4; ++mt)
#pragma unroll
      for (int nt = 0; nt < 4; ++nt)
        acc[mt][nt] = __builtin_amdgcn_mfma_f32_16x16x32_bf16(av[mt], bv[nt], acc[mt][nt], 0, 0, 0);
  }

  // epilogue: C/D layout col = l15, row = quad*4 + r
  if (MODE == 0) {
    int b = rt >> 3;   // 128-row tiles align with batch boundaries
#pragma unroll
    for (int nt = 0; nt < 4; ++nt) {
      int col = ct * 128 + wn * 64 + nt * 16 + l15;
      int sel = col >> 10;
      int h = (col >> 6) & 15;
      int d = col & 63;
      int bh = b * 16 + h;
#pragma unroll
      for (int mt = 0; mt < 4; ++mt) {
        int row0 = rt * 128 + wm * 64 + mt * 16 + quad * 4;
        int n0 = row0 & 1023;
        if (sel == 1) {
          // K: [bh][m][d] layout, lane holds fixed d for 4 consecutive n -> scalar stores
#pragma unroll
          for (int r = 0; r < 4; ++r)
            Kw[((size_t)bh * MP_ + P_ + n0 + r) * D_ + d] = f2bf(acc[mt][nt][r]);
        } else {
          // Q^T / V^T: [bh][d][n] layout -> one packed 8B store of 4 consecutive n
          ushort4 p4;
          if (sel == 0) {
            p4.x = f2bf(acc[mt][nt][0] * 0.125f); p4.y = f2bf(acc[mt][nt][1] * 0.125f);
            p4.z = f2bf(acc[mt][nt][2] * 0.125f); p4.w = f2bf(acc[mt][nt][3] * 0.125f);
            *(ushort4*)&Qt[((size_t)bh * D_ + d) * N_ + n0] = p4;          // softmax scale folded
          } else {
            p4.x = f2bf(acc[mt][nt][0]); p4.y = f2bf(acc[mt][nt][1]);
            p4.z = f2bf(acc[mt][nt][2]); p4.w = f2bf(acc[mt][nt][3]);
            *(ushort4*)&Vt[((size_t)bh * D_ + d) * MP_ + P_ + n0] = p4;
          }
        }
      }
    }
  } else {
#pragma unroll
    for (int nt = 0; nt < 4; ++nt) {
      int col = ct * 128 + wn * 64 + nt * 16 + l15;
      float bs = bias[col];
#pragma unroll
      for (int mt = 0; mt < 4; ++mt) {
#pragma unroll
        for (int r = 0; r < 4; ++r) {
          int row = rt * 128 + wm * 64 + mt * 16 + quad * 4 + r;
          Out[(size_t)row * C_ + col] = acc[mt][nt][r] + bs;   // d_out is FP32
        }
      }
    }
  }
}

// ---------------- attention ----------------
// grid (8 q-tiles, 256 bh), block 256 = 4 waves x 32 q-rows (128 q-rows/block).
// K/V chunks in split-panel LDS layout (64B rows -> conflict-free b128 reads).
// Ps stride 80 (160B, 16B-aligned, bank-spread). Q read from Q^T via per-block gather.
__global__ __launch_bounds__(256) void attn_kernel(const unsigned short* __restrict__ Qt,
                                                   const unsigned short* __restrict__ Kw,
                                                   const unsigned short* __restrict__ Vt,
                                                   unsigned short* __restrict__ Ao) {
  __shared__ unsigned short Ks[4096];      // 2 panels [64 m][32 d]
  __shared__ unsigned short Vs[4096];      // 2 panels [64 d][32 m]
  __shared__ unsigned short Ps[4][32 * 80];
  const int tid = threadIdx.x;
  const int w = tid >> 6, lane = tid & 63;
  const int l15 = lane & 15, quad = lane >> 4, q8 = quad * 8;
  const int qt = blockIdx.x, bh = blockIdx.y;

  // Q A-frags from Q^T[bh][d][n]: elem j of half h = Q[qrow][h*32 + q8 + j]
  short8 aq[2][2];
#pragma unroll
  for (int mq = 0; mq < 2; ++mq) {
    int qrow = qt * 128 + w * 32 + mq * 16 + l15;
    const unsigned short* Qb = Qt + (size_t)bh * D_ * N_ + qrow;
#pragma unroll
    for (int h = 0; h < 2; ++h)
#pragma unroll
      for (int j = 0; j < 8; ++j)
        aq[mq][h][j] = (short)Qb[(size_t)(h * 32 + q8 + j) * N_];
  }

  f32x4 oacc[2][4] = {};
  float den[2][4] = {};

  const unsigned short* Kbh = Kw + (size_t)bh * MP_ * 64;
  const unsigned short* Vbh = Vt + (size_t)bh * 64 * MP_;

  for (int ch = 0; ch < 17; ++ch) {
    __syncthreads();
#pragma unroll
    for (int r = 0; r < 2; ++r) {
      int c = r * 256 + tid;
      int p = c >> 8, mrow = (c >> 2) & 63, s = c & 3;   // chunk -> (panel, row, 16B seg)
      async_cp16(&Ks[(r * 256 + (w << 6)) * 8], Kbh + (size_t)(ch * 64 + mrow) * 64 + p * 32 + s * 8);
      async_cp16(&Vs[(r * 256 + (w << 6)) * 8], Vbh + (size_t)mrow * MP_ + ch * 64 + p * 32 + s * 8);
    }
    __syncthreads();

    unsigned short* Pw = &Ps[w][0];
#pragma unroll
    for (int ct2 = 0; ct2 < 4; ++ct2) {
      short8 b0 = *(const short8*)&Ks[(ct2 * 16 + l15) * 32 + q8];         // d 0..31
      short8 b1 = *(const short8*)&Ks[2048 + (ct2 * 16 + l15) * 32 + q8];  // d 32..63
      int mg = ch * 64 + ct2 * 16 + l15;
      bool valid = (mg < M_);
#pragma unroll
      for (int mq = 0; mq < 2; ++mq) {
        f32x4 s = {};
        s = __builtin_amdgcn_mfma_f32_16x16x32_bf16(aq[mq][0], b0, s, 0, 0, 0);
        s = __builtin_amdgcn_mfma_f32_16x16x32_bf16(aq[mq][1], b1, s, 0, 0, 0);
#pragma unroll
        for (int r = 0; r < 4; ++r) {
          float p = valid ? __expf(s[r]) : 0.f;
          den[mq][r] += p;
          Pw[(mq * 16 + quad * 4 + r) * 80 + ct2 * 16 + l15] = f2bf(p);
        }
      }
    }

    short8 ap[2][2];
#pragma unroll
    for (int mq = 0; mq < 2; ++mq) {
      ap[mq][0] = *(const short8*)&Pw[(mq * 16 + l15) * 80 + q8];
      ap[mq][1] = *(const short8*)&Pw[(mq * 16 + l15) * 80 + 32 + q8];
    }
#pragma unroll
    for (int dt = 0; dt < 4; ++dt) {
      short8 b0 = *(const short8*)&Vs[(dt * 16 + l15) * 32 + q8];          // m 0..31
      short8 b1 = *(const short8*)&Vs[2048 + (dt * 16 + l15) * 32 + q8];   // m 32..63
#pragma unroll
      for (int mq = 0; mq < 2; ++mq) {
        oacc[mq][dt] = __builtin_amdgcn_mfma_f32_16x16x32_bf16(ap[mq][0], b0, oacc[mq][dt], 0, 0, 0);
        oacc[mq][dt] = __builtin_amdgcn_mfma_f32_16x16x32_bf16(ap[mq][1], b1, oacc[mq][dt], 0, 0, 0);
      }
    }
  }

  // reduce denominator across the 16 lanes sharing each q-row
#pragma unroll
  for (int mq = 0; mq < 2; ++mq)
#pragma unroll
    for (int r = 0; r < 4; ++r) {
      float d2 = den[mq][r];
      d2 += __shfl_xor(d2, 1);
      d2 += __shfl_xor(d2, 2);
      d2 += __shfl_xor(d2, 4);
      d2 += __shfl_xor(d2, 8);
      den[mq][r] = 1.f / d2;
    }

  int b = bh >> 4, h = bh & 15;
#pragma unroll
  for (int mq = 0; mq < 2; ++mq)
#pragma unroll
    for (int dt = 0; dt < 4; ++dt)
#pragma unroll
      for (int r = 0; r < 4; ++r) {
        int qrow = qt * 128 + w * 32 + mq * 16 + quad * 4 + r;
        size_t dst = ((size_t)(b * N_ + qrow)) * C_ + h * 64 + dt * 16 + l15;
        Ao[dst] = f2bf(oacc[mq][dt][r] * den[mq][r]);
      }
}

// ---------------- launch ----------------

extern "C" void kernel_launch(void* const* d_in, const int* in_sizes, int n_in,
                              void* d_out, int out_size, void* d_ws, size_t ws_size,
                              hipStream_t stream) {
  const float* x      = (const float*)d_in[0];
  const float* pk     = (const float*)d_in[1];
  const float* pv     = (const float*)d_in[2];
  const float* w_qkv  = (const float*)d_in[3];
  const float* w_proj = (const float*)d_in[4];
  const float* b_proj = (const float*)d_in[5];

  char* ws = (char*)d_ws;
  unsigned short* xb     = (unsigned short*)(ws);                 // 33,554,432 B
  unsigned short* wqkvT  = (unsigned short*)(ws + 33554432);      //  6,291,456 B
  unsigned short* wprojT = (unsigned short*)(ws + 39845888);      //  2,097,152 B
  unsigned short* Qt     = (unsigned short*)(ws + 41943040);      // 33,554,432 B
  unsigned short* Kw     = (unsigned short*)(ws + 75497472);      // 35,651,584 B
  unsigned short* Vt     = (unsigned short*)(ws + 111149056);     // 35,651,584 B
  unsigned short* attn   = xb;  // alias: xb is dead after the QKV GEMM

  cast_x_kernel<<<16384, 256, 0, stream>>>(x, xb);
  transpose_cast_kernel<<<dim3(48, 16), 256, 0, stream>>>(w_qkv, wqkvT, 3072);
  transpose_cast_kernel<<<dim3(16, 16), 256, 0, stream>>>(w_proj, wprojT, 1024);
  prefix_pad_kernel<<<4096, 256, 0, stream>>>(pk, pv, Kw, Vt);

  gemm128<0><<<3072, 256, 0, stream>>>(xb, wqkvT, Qt, Kw, Vt, nullptr, nullptr);
  attn_kernel<<<dim3(8, 256), 256, 0, stream>>>(Qt, Kw, Vt, attn);
  gemm128<1><<<1024, 256, 0, stream>>>(attn, wprojT, nullptr, nullptr, nullptr,
                                       b_proj, (float*)d_out);
}

// Round 5
// 443.421 us; speedup vs baseline: 1.2857x; 1.0178x over previous
//
#include <hip/hip_runtime.h>
#include <stdint.h>

// Problem constants
#define B_  16
#define N_  1024
#define C_  1024
#define H_  16
#define D_  64
#define P_  16
#define M_  1040           // P + N
#define MP_ 1088           // M padded to 17*64

typedef __attribute__((ext_vector_type(8))) short short8;   // 8 bf16 = 4 VGPRs
typedef __attribute__((ext_vector_type(4))) float f32x4;    // MFMA C/D frag

__device__ __forceinline__ unsigned short f2bf(float f) {
  unsigned int u = __float_as_uint(f);
  u += 0x7fffu + ((u >> 16) & 1u);          // RNE
  return (unsigned short)(u >> 16);
}

// async global->LDS, 16B per lane. LDS dest must be wave-uniform base (+lane*16 implicit).
__device__ __forceinline__ void async_cp16(void* lds, const void* g) {
  __builtin_amdgcn_global_load_lds(
      (__attribute__((address_space(1))) void*)(void*)g,
      (__attribute__((address_space(3))) void*)lds,
      16, 0, 0);
}

// ---------------- prep kernels (merged: 2 launches) ----------------

// blocks [0,16384): x fp32->bf16 cast.  blocks [16384,20480): K prefix/pad + V^T prefix/pad.
__global__ void prep_kernel(const float* __restrict__ x, const float* __restrict__ pk,
                            const float* __restrict__ pv, unsigned short* __restrict__ xb,
                            unsigned short* __restrict__ Kw, unsigned short* __restrict__ Vt) {
  int bid = blockIdx.x;
  if (bid < 16384) {
    int i = (bid * 256 + threadIdx.x) * 4;
    float4 v = *(const float4*)(x + i);
    ushort4 o;
    o.x = f2bf(v.x); o.y = f2bf(v.y); o.z = f2bf(v.z); o.w = f2bf(v.w);
    *(ushort4*)(xb + i) = o;
  } else {
    int idx = (bid - 16384) * 256 + threadIdx.x;   // 1,048,576
    {  // K: d fastest (coalesced dst + src)
      int d = idx & 63, rr = (idx >> 6) & 63, bh = idx >> 12;
      int row = (rr < P_) ? rr : (1024 + rr);
      float kv = 0.f;
      if (rr < P_) { int b = bh >> 4, h = bh & 15; kv = pk[(b * P_ + rr) * C_ + h * D_ + d]; }
      Kw[((size_t)bh * MP_ + row) * D_ + d] = f2bf(kv);
    }
    {  // V^T: row-slot fastest (coalesced dst; tiny strided src absorbed by L2)
      int mm = idx & 63, d = (idx >> 6) & 63, bh = idx >> 12;
      int row = (mm < P_) ? mm : (1024 + mm);
      float vv = 0.f;
      if (mm < P_) { int b = bh >> 4, h = bh & 15; vv = pv[(b * P_ + mm) * C_ + h * D_ + d]; }
      Vt[((size_t)bh * D_ + d) * MP_ + row] = f2bf(vv);
    }
  }
}

// both weight transposes in one launch: [1024 k][cols n] fp32 -> [n][1024 k] bf16.
// blockIdx.x < 48 -> w_qkv (cols=3072); else w_proj (cols=1024).
__global__ void transpose_cast_kernel(const float* __restrict__ wqkv,
                                      const float* __restrict__ wproj,
                                      unsigned short* __restrict__ oqkv,
                                      unsigned short* __restrict__ oproj) {
  __shared__ unsigned short t[64][68];   // pad 68: breaks bank aliasing on strided read
  int bx = blockIdx.x;
  const float* in;  unsigned short* out;  int cols, n0;
  if (bx < 48) { in = wqkv;  out = oqkv;  cols = 3072; n0 = bx * 64; }
  else         { in = wproj; out = oproj; cols = 1024; n0 = (bx - 48) * 64; }
  int k0 = blockIdx.y * 64;
  int tid = threadIdx.x;
#pragma unroll
  for (int i = 0; i < 16; ++i) {
    int e = i * 256 + tid;
    int kk = e >> 6, nn = e & 63;
    t[kk][nn] = f2bf(in[(size_t)(k0 + kk) * cols + n0 + nn]);
  }
  __syncthreads();
#pragma unroll
  for (int i = 0; i < 16; ++i) {
    int e = i * 256 + tid;
    int nn = e >> 6, kk = e & 63;
    out[(size_t)(n0 + nn) * 1024 + k0 + kk] = t[kk][nn];
  }
}

// ---------------- GEMM: C[M,Ncols] = A[M,1024] * Bt[Ncols,1024]^T ----------------
// 128x128 tile, BK=64 (two [128m][32k] LDS panels per operand -> 32 MFMA per barrier
// pair, 16 drains instead of 32; panel rows stay 64B = conflict-free b128 reads).
// 1-D grid with 32rt x 8ct supertile swizzle for L2 locality.
// MODE 0: qkv epilogue (Q^T pre-scaled, Kw, V^T). MODE 1: proj epilogue (+bias, FP32 out).
template <int MODE>
__global__ __launch_bounds__(256) void gemm128(const unsigned short* __restrict__ A,
                                               const unsigned short* __restrict__ Bt,
                                               unsigned short* __restrict__ Qt,
                                               unsigned short* __restrict__ Kw,
                                               unsigned short* __restrict__ Vt,
                                               const float* __restrict__ bias,
                                               float* __restrict__ Out) {
  __shared__ unsigned short As[2 * 128 * 32];   // [panel kk][m][32k]
  __shared__ unsigned short Bs[2 * 128 * 32];
  const int tid = threadIdx.x;
  const int w = tid >> 6, lane = tid & 63;
  const int l15 = lane & 15, quad = lane >> 4, q8 = quad * 8;
  const int wm = w & 1, wn = w >> 1;

  // supertile swizzle (RT=128 rows of tiles in both modes)
  const int id = blockIdx.x;
  const int st = id >> 8, local = id & 255;
  const int rt = (st & 3) * 32 + (local & 31);
  const int ct = (st >> 2) * 8 + (local >> 5);

  f32x4 acc[4][4] = {};
  const unsigned short* Abase = A + (size_t)rt * 128 * 1024;
  const unsigned short* Bbase = Bt + (size_t)ct * 128 * 1024;

  for (int k0 = 0; k0 < 1024; k0 += 64) {
    __syncthreads();
#pragma unroll
    for (int r = 0; r < 4; ++r) {
      int c = r * 256 + tid;                 // 1024 chunks of 16B per 16KB tile
      int p = c >> 9, m = (c >> 2) & 127, kq = (c & 3) * 8;
      async_cp16(&As[(r * 256 + (w << 6)) * 8], Abase + m * 1024 + k0 + p * 32 + kq);
      async_cp16(&Bs[(r * 256 + (w << 6)) * 8], Bbase + m * 1024 + k0 + p * 32 + kq);
    }
    __syncthreads();

#pragma unroll
    for (int kk = 0; kk < 2; ++kk) {
      short8 av[4], bv[4];
#pragma unroll
      for (int mt = 0; mt < 4; ++mt)
        av[mt] = *(const short8*)&As[kk * 4096 + (wm * 64 + mt * 16 + l15) * 32 + q8];
#pragma unroll
      for (int nt = 0; nt < 4; ++nt)
        bv[nt] = *(const short8*)&Bs[kk * 4096 + (wn * 64 + nt * 16 + l15) * 32 + q8];
#pragma unroll
      for (int mt = 0; mt < 4; ++mt)
#pragma unroll
        for (int nt = 0; nt < 4; ++nt)
          acc[mt][nt] = __builtin_amdgcn_mfma_f32_16x16x32_bf16(av[mt], bv[nt], acc[mt][nt], 0, 0, 0);
    }
  }

  // epilogue: C/D layout col = l15, row = quad*4 + r
  if (MODE == 0) {
    int b = rt >> 3;   // 128-row tiles align with batch boundaries
#pragma unroll
    for (int nt = 0; nt < 4; ++nt) {
      int col = ct * 128 + wn * 64 + nt * 16 + l15;
      int sel = col >> 10;
      int h = (col >> 6) & 15;
      int d = col & 63;
      int bh = b * 16 + h;
#pragma unroll
      for (int mt = 0; mt < 4; ++mt) {
        int row0 = rt * 128 + wm * 64 + mt * 16 + quad * 4;
        int n0 = row0 & 1023;
        if (sel == 1) {
          // K: [bh][m][d] layout, lane holds fixed d for 4 consecutive n -> scalar stores
#pragma unroll
          for (int r = 0; r < 4; ++r)
            Kw[((size_t)bh * MP_ + P_ + n0 + r) * D_ + d] = f2bf(acc[mt][nt][r]);
        } else {
          // Q^T / V^T: [bh][d][n] layout -> one packed 8B store of 4 consecutive n
          ushort4 p4;
          if (sel == 0) {
            p4.x = f2bf(acc[mt][nt][0] * 0.125f); p4.y = f2bf(acc[mt][nt][1] * 0.125f);
            p4.z = f2bf(acc[mt][nt][2] * 0.125f); p4.w = f2bf(acc[mt][nt][3] * 0.125f);
            *(ushort4*)&Qt[((size_t)bh * D_ + d) * N_ + n0] = p4;          // softmax scale folded
          } else {
            p4.x = f2bf(acc[mt][nt][0]); p4.y = f2bf(acc[mt][nt][1]);
            p4.z = f2bf(acc[mt][nt][2]); p4.w = f2bf(acc[mt][nt][3]);
            *(ushort4*)&Vt[((size_t)bh * D_ + d) * MP_ + P_ + n0] = p4;
          }
        }
      }
    }
  } else {
#pragma unroll
    for (int nt = 0; nt < 4; ++nt) {
      int col = ct * 128 + wn * 64 + nt * 16 + l15;
      float bs = bias[col];
#pragma unroll
      for (int mt = 0; mt < 4; ++mt) {
#pragma unroll
        for (int r = 0; r < 4; ++r) {
          int row = rt * 128 + wm * 64 + mt * 16 + quad * 4 + r;
          Out[(size_t)row * C_ + col] = acc[mt][nt][r] + bs;   // d_out is FP32
        }
      }
    }
  }
}

// ---------------- attention ----------------
// grid (8 q-tiles, 256 bh), block 256 = 4 waves x 32 q-rows (128 q-rows/block).
// K/V chunks in split-panel LDS layout (64B rows -> conflict-free b128 reads).
// Ps stride 80 (160B, 16B-aligned, bank-spread). Q read from Q^T via per-block gather.
__global__ __launch_bounds__(256) void attn_kernel(const unsigned short* __restrict__ Qt,
                                                   const unsigned short* __restrict__ Kw,
                                                   const unsigned short* __restrict__ Vt,
                                                   unsigned short* __restrict__ Ao) {
  __shared__ unsigned short Ks[4096];      // 2 panels [64 m][32 d]
  __shared__ unsigned short Vs[4096];      // 2 panels [64 d][32 m]
  __shared__ unsigned short Ps[4][32 * 80];
  const int tid = threadIdx.x;
  const int w = tid >> 6, lane = tid & 63;
  const int l15 = lane & 15, quad = lane >> 4, q8 = quad * 8;
  const int qt = blockIdx.x, bh = blockIdx.y;

  // Q A-frags from Q^T[bh][d][n]: elem j of half h = Q[qrow][h*32 + q8 + j]
  short8 aq[2][2];
#pragma unroll
  for (int mq = 0; mq < 2; ++mq) {
    int qrow = qt * 128 + w * 32 + mq * 16 + l15;
    const unsigned short* Qb = Qt + (size_t)bh * D_ * N_ + qrow;
#pragma unroll
    for (int h = 0; h < 2; ++h)
#pragma unroll
      for (int j = 0; j < 8; ++j)
        aq[mq][h][j] = (short)Qb[(size_t)(h * 32 + q8 + j) * N_];
  }

  f32x4 oacc[2][4] = {};
  float den[2][4] = {};

  const unsigned short* Kbh = Kw + (size_t)bh * MP_ * 64;
  const unsigned short* Vbh = Vt + (size_t)bh * 64 * MP_;

  for (int ch = 0; ch < 17; ++ch) {
    __syncthreads();
#pragma unroll
    for (int r = 0; r < 2; ++r) {
      int c = r * 256 + tid;
      int p = c >> 8, mrow = (c >> 2) & 63, s = c & 3;   // chunk -> (panel, row, 16B seg)
      async_cp16(&Ks[(r * 256 + (w << 6)) * 8], Kbh + (size_t)(ch * 64 + mrow) * 64 + p * 32 + s * 8);
      async_cp16(&Vs[(r * 256 + (w << 6)) * 8], Vbh + (size_t)mrow * MP_ + ch * 64 + p * 32 + s * 8);
    }
    __syncthreads();

    unsigned short* Pw = &Ps[w][0];
#pragma unroll
    for (int ct2 = 0; ct2 < 4; ++ct2) {
      short8 b0 = *(const short8*)&Ks[(ct2 * 16 + l15) * 32 + q8];         // d 0..31
      short8 b1 = *(const short8*)&Ks[2048 + (ct2 * 16 + l15) * 32 + q8];  // d 32..63
      int mg = ch * 64 + ct2 * 16 + l15;
      bool valid = (mg < M_);
#pragma unroll
      for (int mq = 0; mq < 2; ++mq) {
        f32x4 s = {};
        s = __builtin_amdgcn_mfma_f32_16x16x32_bf16(aq[mq][0], b0, s, 0, 0, 0);
        s = __builtin_amdgcn_mfma_f32_16x16x32_bf16(aq[mq][1], b1, s, 0, 0, 0);
#pragma unroll
        for (int r = 0; r < 4; ++r) {
          float p = valid ? __expf(s[r]) : 0.f;
          den[mq][r] += p;
          Pw[(mq * 16 + quad * 4 + r) * 80 + ct2 * 16 + l15] = f2bf(p);
        }
      }
    }

    short8 ap[2][2];
#pragma unroll
    for (int mq = 0; mq < 2; ++mq) {
      ap[mq][0] = *(const short8*)&Pw[(mq * 16 + l15) * 80 + q8];
      ap[mq][1] = *(const short8*)&Pw[(mq * 16 + l15) * 80 + 32 + q8];
    }
#pragma unroll
    for (int dt = 0; dt < 4; ++dt) {
      short8 b0 = *(const short8*)&Vs[(dt * 16 + l15) * 32 + q8];          // m 0..31
      short8 b1 = *(const short8*)&Vs[2048 + (dt * 16 + l15) * 32 + q8];   // m 32..63
#pragma unroll
      for (int mq = 0; mq < 2; ++mq) {
        oacc[mq][dt] = __builtin_amdgcn_mfma_f32_16x16x32_bf16(ap[mq][0], b0, oacc[mq][dt], 0, 0, 0);
        oacc[mq][dt] = __builtin_amdgcn_mfma_f32_16x16x32_bf16(ap[mq][1], b1, oacc[mq][dt], 0, 0, 0);
      }
    }
  }

  // reduce denominator across the 16 lanes sharing each q-row
#pragma unroll
  for (int mq = 0; mq < 2; ++mq)
#pragma unroll
    for (int r = 0; r < 4; ++r) {
      float d2 = den[mq][r];
      d2 += __shfl_xor(d2, 1);
      d2 += __shfl_xor(d2, 2);
      d2 += __shfl_xor(d2, 4);
      d2 += __shfl_xor(d2, 8);
      den[mq][r] = 1.f / d2;
    }

  int b = bh >> 4, h = bh & 15;
#pragma unroll
  for (int mq = 0; mq < 2; ++mq)
#pragma unroll
    for (int dt = 0; dt < 4; ++dt)
#pragma unroll
      for (int r = 0; r < 4; ++r) {
        int qrow = qt * 128 + w * 32 + mq * 16 + quad * 4 + r;
        size_t dst = ((size_t)(b * N_ + qrow)) * C_ + h * 64 + dt * 16 + l15;
        Ao[dst] = f2bf(oacc[mq][dt][r] * den[mq][r]);
      }
}

// ---------------- launch ----------------

extern "C" void kernel_launch(void* const* d_in, const int* in_sizes, int n_in,
                              void* d_out, int out_size, void* d_ws, size_t ws_size,
                              hipStream_t stream) {
  const float* x      = (const float*)d_in[0];
  const float* pk     = (const float*)d_in[1];
  const float* pv     = (const float*)d_in[2];
  const float* w_qkv  = (const float*)d_in[3];
  const float* w_proj = (const float*)d_in[4];
  const float* b_proj = (const float*)d_in[5];

  char* ws = (char*)d_ws;
  unsigned short* xb     = (unsigned short*)(ws);                 // 33,554,432 B
  unsigned short* wqkvT  = (unsigned short*)(ws + 33554432);      //  6,291,456 B
  unsigned short* wprojT = (unsigned short*)(ws + 39845888);      //  2,097,152 B
  unsigned short* Qt     = (unsigned short*)(ws + 41943040);      // 33,554,432 B
  unsigned short* Kw     = (unsigned short*)(ws + 75497472);      // 35,651,584 B
  unsigned short* Vt     = (unsigned short*)(ws + 111149056);     // 35,651,584 B
  unsigned short* attn   = xb;  // alias: xb is dead after the QKV GEMM

  prep_kernel<<<20480, 256, 0, stream>>>(x, pk, pv, xb, Kw, Vt);
  transpose_cast_kernel<<<dim3(64, 16), 256, 0, stream>>>(w_qkv, w_proj, wqkvT, wprojT);

  gemm128<0><<<3072, 256, 0, stream>>>(xb, wqkvT, Qt, Kw, Vt, nullptr, nullptr);
  attn_kernel<<<dim3(8, 256), 256, 0, stream>>>(Qt, Kw, Vt, attn);
  gemm128<1><<<1024, 256, 0, stream>>>(attn, wprojT, nullptr, nullptr, nullptr,
                                       b_proj, (float*)d_out);
}